// Round 1
// baseline (3004.551 us; speedup 1.0000x reference)
//
#include <hip/hip_runtime.h>
#include <hip/hip_bf16.h>

#define D 128

typedef __attribute__((ext_vector_type(8))) short bf16x8;
typedef __attribute__((ext_vector_type(4))) float f32x4;

// fp32 -> bf16 round-to-nearest-even, bit-level (no API dependency)
__device__ inline unsigned short f2bf(float f) {
    union { float f; unsigned u; } v; v.f = f;
    unsigned r = v.u + 0x7FFFu + ((v.u >> 16) & 1u);
    return (unsigned short)(r >> 16);
}

// ---------------------------------------------------------------------------
// Scatter: for each edge e, agg[src[e]] += x[dst[e]] * w[e]; wsum[src[e]] += w[e]
// 32 lanes per edge, float4 per lane (32*4 = 128 features). 8 edges / block.
// ---------------------------------------------------------------------------
__global__ void scatter_kernel(const float* __restrict__ feat,
                               const int* __restrict__ src,
                               const int* __restrict__ dst,
                               const float* __restrict__ w,
                               float* __restrict__ agg,
                               float* __restrict__ wsum,
                               int E) {
    int e = blockIdx.x * 8 + (threadIdx.x >> 5);
    if (e >= E) return;
    int l = threadIdx.x & 31;
    int s = src[e];
    int d = dst[e];
    float we = w[e];
    const float4 v = *(const float4*)(feat + (size_t)d * D + l * 4);
    float* base = agg + (size_t)s * D + l * 4;
    unsafeAtomicAdd(base + 0, v.x * we);
    unsafeAtomicAdd(base + 1, v.y * we);
    unsafeAtomicAdd(base + 2, v.z * we);
    unsafeAtomicAdd(base + 3, v.w * we);
    if (l == 0) unsafeAtomicAdd(wsum + s, we);
}

__global__ void invw_kernel(float* __restrict__ wsum, int n) {
    int i = blockIdx.x * blockDim.x + threadIdx.x;
    if (i < n) wsum[i] = 1.0f / fmaxf(wsum[i], 1e-12f);
}

// ---------------------------------------------------------------------------
// Fused SAGE GEMM: out[r][o] = relu( sum_k A[r][k] * W[o][k] + b[o] )
// A[r][k] = xpart[r][k]               (k < 128)
//         = agg[r][k-128] * invw[r]   (k >= 128)
// Tile: 128 rows x 128 cols, K=256 in 4 chunks of 64. bf16 MFMA 16x16x32.
// Block = 256 threads (4 waves); wave w computes rows [w*32, w*32+32).
// ---------------------------------------------------------------------------
__global__ void __launch_bounds__(256)
sage_gemm(const float* __restrict__ xpart,
          const float* __restrict__ agg,
          const float* __restrict__ invw,
          const float* __restrict__ W,     // [128][256] row-major
          const float* __restrict__ bias,  // [128]
          float* __restrict__ out,         // [n][128]
          int n) {
    __shared__ short As[128][72];   // 128 rows x 64 k, +8 pad (2-way bank alias = free)
    __shared__ short Bs[128][72];

    const int row0 = blockIdx.x * 128;
    const int tid  = threadIdx.x;
    const int wave = tid >> 6;
    const int lane = tid & 63;
    const int quad = lane >> 4;   // 0..3
    const int l16  = lane & 15;

    f32x4 acc[2][8];
#pragma unroll
    for (int rt = 0; rt < 2; ++rt)
#pragma unroll
        for (int c = 0; c < 8; ++c)
            acc[rt][c] = (f32x4){0.f, 0.f, 0.f, 0.f};

#pragma unroll
    for (int kc = 0; kc < 4; ++kc) {
        const bool isneigh = (kc >= 2);
        const int cbase = isneigh ? (kc - 2) * 64 : kc * 64;
        const float* asrc = isneigh ? agg : xpart;

        // Stage A chunk (fp32 -> bf16) and W chunk
#pragma unroll
        for (int i = 0; i < 8; ++i) {
            int e = i * 256 + tid;          // 0..2047
            int r = e >> 4;                  // 0..127
            int c4 = (e & 15) * 4;           // 0..60
            int row = row0 + r;
            if (row >= n) row = n - 1;       // clamp (garbage rows never stored)
            float4 v = *(const float4*)(asrc + (size_t)row * D + cbase + c4);
            if (isneigh) {
                float iw = invw[row];
                v.x *= iw; v.y *= iw; v.z *= iw; v.w *= iw;
            }
            unsigned lo = (unsigned)f2bf(v.x) | ((unsigned)f2bf(v.y) << 16);
            unsigned hi = (unsigned)f2bf(v.z) | ((unsigned)f2bf(v.w) << 16);
            *(uint2*)(&As[r][c4]) = make_uint2(lo, hi);

            float4 wv = *(const float4*)(W + (size_t)r * 256 + kc * 64 + c4);
            unsigned wlo = (unsigned)f2bf(wv.x) | ((unsigned)f2bf(wv.y) << 16);
            unsigned whi = (unsigned)f2bf(wv.z) | ((unsigned)f2bf(wv.w) << 16);
            *(uint2*)(&Bs[r][c4]) = make_uint2(wlo, whi);
        }
        __syncthreads();

#pragma unroll
        for (int ks = 0; ks < 2; ++ks) {
            const int koff = ks * 32 + quad * 8;
            bf16x8 a0 = *(const bf16x8*)&As[wave * 32 + l16][koff];
            bf16x8 a1 = *(const bf16x8*)&As[wave * 32 + 16 + l16][koff];
#pragma unroll
            for (int c = 0; c < 8; ++c) {
                bf16x8 b = *(const bf16x8*)&Bs[c * 16 + l16][koff];
                acc[0][c] = __builtin_amdgcn_mfma_f32_16x16x32_bf16(a0, b, acc[0][c], 0, 0, 0);
                acc[1][c] = __builtin_amdgcn_mfma_f32_16x16x32_bf16(a1, b, acc[1][c], 0, 0, 0);
            }
        }
        __syncthreads();
    }

    // Epilogue: bias + relu + store fp32. C/D layout: col=lane&15, row=quad*4+reg
    float bvals[8];
#pragma unroll
    for (int c = 0; c < 8; ++c) bvals[c] = bias[c * 16 + l16];

#pragma unroll
    for (int rt = 0; rt < 2; ++rt) {
#pragma unroll
        for (int reg = 0; reg < 4; ++reg) {
            int row = row0 + wave * 32 + rt * 16 + quad * 4 + reg;
            if (row < n) {
                float* orow = out + (size_t)row * D;
#pragma unroll
                for (int c = 0; c < 8; ++c) {
                    float v = acc[rt][c][reg] + bvals[c];
                    orow[c * 16 + l16] = fmaxf(v, 0.0f);
                }
            }
        }
    }
}

// ---------------------------------------------------------------------------
// Row L2-normalize in place: h[r] /= max(||h[r]||, 1e-12). One wave per row.
// ---------------------------------------------------------------------------
__global__ void normalize_kernel(float* __restrict__ h, int n) {
    int wave = threadIdx.x >> 6;
    int lane = threadIdx.x & 63;
    int row = blockIdx.x * 4 + wave;
    if (row >= n) return;
    float* p = h + (size_t)row * D + lane * 2;
    float2 v = *(float2*)p;
    float ss = v.x * v.x + v.y * v.y;
#pragma unroll
    for (int o = 32; o > 0; o >>= 1) ss += __shfl_xor(ss, o);
    float inv = 1.0f / fmaxf(sqrtf(ss), 1e-12f);
    v.x *= inv; v.y *= inv;
    *(float2*)p = v;
}

extern "C" void kernel_launch(void* const* d_in, const int* in_sizes, int n_in,
                              void* d_out, int out_size, void* d_ws, size_t ws_size,
                              hipStream_t stream) {
    const float* x  = (const float*)d_in[0];
    const int*   ei = (const int*)d_in[1];   // [2, E]: row 0 = src, row 1 = dst
    const float* ew = (const float*)d_in[2];
    const float* W1 = (const float*)d_in[3];
    const float* b1 = (const float*)d_in[4];
    const float* W2 = (const float*)d_in[5];
    const float* b2 = (const float*)d_in[6];
    float* out = (float*)d_out;

    const int E = in_sizes[2];        // edge_weight element count
    const int N = in_sizes[0] / D;    // 100000

    const int* src = ei;
    const int* dst = ei + E;

    // workspace layout: agg [N*D f32] | wsum [N f32] | h [N*D f32]
    char* ws = (char*)d_ws;
    const size_t aggBytes  = (size_t)N * D * sizeof(float);
    const size_t wsumBytes = (size_t)N * sizeof(float);
    float* agg  = (float*)ws;
    float* wsum = (float*)(ws + aggBytes);
    float* h    = (float*)(ws + aggBytes + ((wsumBytes + 255) & ~(size_t)255));

    const int scatterGrid = (E + 7) / 8;
    const int gemmGrid    = (N + 127) / 128;

    // ---- Layer 1 ----
    hipMemsetAsync(d_ws, 0, aggBytes + wsumBytes, stream);
    scatter_kernel<<<scatterGrid, 256, 0, stream>>>(x, src, dst, ew, agg, wsum, E);
    invw_kernel<<<(N + 255) / 256, 256, 0, stream>>>(wsum, N);
    sage_gemm<<<gemmGrid, 256, 0, stream>>>(x, agg, wsum, W1, b1, h, N);

    // ---- Layer 2 ----
    hipMemsetAsync(d_ws, 0, aggBytes + wsumBytes, stream);
    scatter_kernel<<<scatterGrid, 256, 0, stream>>>(h, src, dst, ew, agg, wsum, E);
    invw_kernel<<<(N + 255) / 256, 256, 0, stream>>>(wsum, N);
    sage_gemm<<<gemmGrid, 256, 0, stream>>>(h, agg, wsum, W2, b2, out, N);

    // ---- Normalize ----
    normalize_kernel<<<(N + 3) / 4, 256, 0, stream>>>(out, N);
}

// Round 2
// 464.310 us; speedup vs baseline: 6.4710x; 6.4710x over previous
//
#include <hip/hip_runtime.h>
#include <hip/hip_bf16.h>

#define D 128

typedef __attribute__((ext_vector_type(8))) short bf16x8;
typedef __attribute__((ext_vector_type(4))) float f32x4;

// fp32 -> bf16 round-to-nearest-even, bit-level
__device__ inline unsigned short f2bf(float f) {
    union { float f; unsigned u; } v; v.f = f;
    unsigned r = v.u + 0x7FFFu + ((v.u >> 16) & 1u);
    return (unsigned short)(r >> 16);
}

// ---------------------------------------------------------------------------
// CSR build: histogram of src, exclusive scan -> rowptr, bucket-fill dst/w.
// 800k int atomics replace 205M float atomics of the scatter approach.
// ---------------------------------------------------------------------------
__global__ void hist_kernel(const int* __restrict__ src, int* __restrict__ deg, int E) {
    int i = blockIdx.x * blockDim.x + threadIdx.x;
    if (i < E) atomicAdd(&deg[src[i]], 1);
}

// Block-level inclusive scan of deg chunks (1024/block); block sums to bsum.
__global__ void scan1_kernel(const int* __restrict__ deg, int* __restrict__ rowptr,
                             int* __restrict__ bsum, int n) {
    __shared__ int s[1024];
    int t = threadIdx.x;
    int i = blockIdx.x * 1024 + t;
    int v = (i < n) ? deg[i] : 0;
    s[t] = v;
    __syncthreads();
    for (int off = 1; off < 1024; off <<= 1) {
        int x = (t >= off) ? s[t - off] : 0;
        __syncthreads();
        s[t] += x;
        __syncthreads();
    }
    if (i < n) rowptr[i + 1] = s[t];
    if (t == 1023) bsum[blockIdx.x] = s[t];
}

// Scan of block sums -> exclusive block offsets (supports up to 1024 blocks).
__global__ void scan2_kernel(int* __restrict__ bsum, int nb) {
    __shared__ int s[1024];
    int t = threadIdx.x;
    int v = (t < nb) ? bsum[t] : 0;
    s[t] = v;
    __syncthreads();
    for (int off = 1; off < 1024; off <<= 1) {
        int x = (t >= off) ? s[t - off] : 0;
        __syncthreads();
        s[t] += x;
        __syncthreads();
    }
    if (t < nb) bsum[t] = (t == 0) ? 0 : s[t - 1];
}

// Apply block offsets; emit cursor (= exclusive start per node) for the fill.
__global__ void scan3_kernel(const int* __restrict__ deg, const int* __restrict__ bsum,
                             int* __restrict__ rowptr, int* __restrict__ cursor, int n) {
    int i = blockIdx.x * blockDim.x + threadIdx.x;
    if (i < n) {
        int v = rowptr[i + 1] + bsum[i >> 10];
        rowptr[i + 1] = v;
        cursor[i] = v - deg[i];
    }
    if (i == 0) rowptr[0] = 0;
}

__global__ void fill_kernel(const int* __restrict__ src, const int* __restrict__ dst,
                            const float* __restrict__ w, int* __restrict__ cursor,
                            int* __restrict__ edst, float* __restrict__ eww, int E) {
    int i = blockIdx.x * blockDim.x + threadIdx.x;
    if (i < E) {
        int p = atomicAdd(&cursor[src[i]], 1);
        edst[p] = dst[i];
        eww[p] = w[i];
    }
}

// ---------------------------------------------------------------------------
// Gather aggregation: one wave per node. neigh[node] = sum_e w_e*feat[dst_e]
//                                                      / max(sum_e w_e, eps)
// 64 lanes x float2 = the full 128-float row; gathers are 512B coalesced.
// ---------------------------------------------------------------------------
__global__ void aggregate_kernel(const float* __restrict__ feat,
                                 const int* __restrict__ rowptr,
                                 const int* __restrict__ edst,
                                 const float* __restrict__ eww,
                                 float* __restrict__ neigh, int n) {
    int node = blockIdx.x * 4 + (threadIdx.x >> 6);
    if (node >= n) return;
    int lane = threadIdx.x & 63;
    int beg = rowptr[node];
    int end = rowptr[node + 1];
    float ax = 0.f, ay = 0.f, wsum = 0.f;
    int j = beg;
    for (; j + 1 < end; j += 2) {   // 2-edge unroll: two gathers in flight
        int d0 = edst[j], d1 = edst[j + 1];
        float w0 = eww[j], w1 = eww[j + 1];
        float2 v0 = *(const float2*)(feat + (size_t)d0 * D + lane * 2);
        float2 v1 = *(const float2*)(feat + (size_t)d1 * D + lane * 2);
        ax += v0.x * w0 + v1.x * w1;
        ay += v0.y * w0 + v1.y * w1;
        wsum += w0 + w1;
    }
    if (j < end) {
        int d0 = edst[j];
        float w0 = eww[j];
        float2 v0 = *(const float2*)(feat + (size_t)d0 * D + lane * 2);
        ax += v0.x * w0;
        ay += v0.y * w0;
        wsum += w0;
    }
    float inv = 1.0f / fmaxf(wsum, 1e-12f);
    float2 o = {ax * inv, ay * inv};
    *(float2*)(neigh + (size_t)node * D + lane * 2) = o;
}

// ---------------------------------------------------------------------------
// Fused SAGE GEMM: out[r][o] = relu( sum_k A[r][k] * W[o][k] + b[o] )
// A[r][k] = xpart[r][k] (k<128) else neigh[r][k-128]  (already mean-divided)
// 128x128 tile, K=256 in 4 chunks of 64, bf16 MFMA 16x16x32.
// ---------------------------------------------------------------------------
__global__ void __launch_bounds__(256)
sage_gemm(const float* __restrict__ xpart,
          const float* __restrict__ neigh,
          const float* __restrict__ W,     // [128][256] row-major
          const float* __restrict__ bias,  // [128]
          float* __restrict__ out,         // [n][128]
          int n) {
    __shared__ short As[128][72];   // +8 pad: 2-way bank alias = free
    __shared__ short Bs[128][72];

    const int row0 = blockIdx.x * 128;
    const int tid  = threadIdx.x;
    const int wave = tid >> 6;
    const int lane = tid & 63;
    const int quad = lane >> 4;
    const int l16  = lane & 15;

    f32x4 acc[2][8];
#pragma unroll
    for (int rt = 0; rt < 2; ++rt)
#pragma unroll
        for (int c = 0; c < 8; ++c)
            acc[rt][c] = (f32x4){0.f, 0.f, 0.f, 0.f};

#pragma unroll
    for (int kc = 0; kc < 4; ++kc) {
        const float* asrc = (kc >= 2) ? neigh : xpart;
        const int cbase = (kc & 1) * 64;

#pragma unroll
        for (int i = 0; i < 8; ++i) {
            int e = i * 256 + tid;
            int r = e >> 4;
            int c4 = (e & 15) * 4;
            int row = row0 + r;
            if (row >= n) row = n - 1;     // clamp; garbage rows never stored
            float4 v = *(const float4*)(asrc + (size_t)row * D + cbase + c4);
            unsigned lo = (unsigned)f2bf(v.x) | ((unsigned)f2bf(v.y) << 16);
            unsigned hi = (unsigned)f2bf(v.z) | ((unsigned)f2bf(v.w) << 16);
            *(uint2*)(&As[r][c4]) = make_uint2(lo, hi);

            float4 wv = *(const float4*)(W + (size_t)r * 256 + kc * 64 + c4);
            unsigned wlo = (unsigned)f2bf(wv.x) | ((unsigned)f2bf(wv.y) << 16);
            unsigned whi = (unsigned)f2bf(wv.z) | ((unsigned)f2bf(wv.w) << 16);
            *(uint2*)(&Bs[r][c4]) = make_uint2(wlo, whi);
        }
        __syncthreads();

#pragma unroll
        for (int ks = 0; ks < 2; ++ks) {
            const int koff = ks * 32 + quad * 8;
            bf16x8 a0 = *(const bf16x8*)&As[wave * 32 + l16][koff];
            bf16x8 a1 = *(const bf16x8*)&As[wave * 32 + 16 + l16][koff];
#pragma unroll
            for (int c = 0; c < 8; ++c) {
                bf16x8 b = *(const bf16x8*)&Bs[c * 16 + l16][koff];
                acc[0][c] = __builtin_amdgcn_mfma_f32_16x16x32_bf16(a0, b, acc[0][c], 0, 0, 0);
                acc[1][c] = __builtin_amdgcn_mfma_f32_16x16x32_bf16(a1, b, acc[1][c], 0, 0, 0);
            }
        }
        __syncthreads();
    }

    float bvals[8];
#pragma unroll
    for (int c = 0; c < 8; ++c) bvals[c] = bias[c * 16 + l16];

#pragma unroll
    for (int rt = 0; rt < 2; ++rt) {
#pragma unroll
        for (int reg = 0; reg < 4; ++reg) {
            int row = row0 + wave * 32 + rt * 16 + quad * 4 + reg;
            if (row < n) {
                float* orow = out + (size_t)row * D;
#pragma unroll
                for (int c = 0; c < 8; ++c) {
                    float v = acc[rt][c][reg] + bvals[c];
                    orow[c * 16 + l16] = fmaxf(v, 0.0f);
                }
            }
        }
    }
}

// ---------------------------------------------------------------------------
// Row L2-normalize in place. One wave per row.
// ---------------------------------------------------------------------------
__global__ void normalize_kernel(float* __restrict__ h, int n) {
    int wave = threadIdx.x >> 6;
    int lane = threadIdx.x & 63;
    int row = blockIdx.x * 4 + wave;
    if (row >= n) return;
    float* p = h + (size_t)row * D + lane * 2;
    float2 v = *(float2*)p;
    float ss = v.x * v.x + v.y * v.y;
#pragma unroll
    for (int o = 32; o > 0; o >>= 1) ss += __shfl_xor(ss, o);
    float inv = 1.0f / fmaxf(sqrtf(ss), 1e-12f);
    v.x *= inv; v.y *= inv;
    *(float2*)p = v;
}

extern "C" void kernel_launch(void* const* d_in, const int* in_sizes, int n_in,
                              void* d_out, int out_size, void* d_ws, size_t ws_size,
                              hipStream_t stream) {
    const float* x  = (const float*)d_in[0];
    const int*   ei = (const int*)d_in[1];   // [2, E]: row 0 = src, row 1 = dst
    const float* ew = (const float*)d_in[2];
    const float* W1 = (const float*)d_in[3];
    const float* b1 = (const float*)d_in[4];
    const float* W2 = (const float*)d_in[5];
    const float* b2 = (const float*)d_in[6];
    float* out = (float*)d_out;

    const int E = in_sizes[2];
    const int N = in_sizes[0] / D;

    const int* src = ei;
    const int* dst = ei + E;

    // workspace layout
    char* p = (char*)d_ws;
    auto alloc = [&](size_t bytes) { char* r = p; p += (bytes + 255) & ~(size_t)255; return r; };
    float* neigh  = (float*)alloc((size_t)N * D * sizeof(float));  // 51.2 MB
    float* h      = (float*)alloc((size_t)N * D * sizeof(float));  // 51.2 MB
    int*   edst   = (int*)  alloc((size_t)E * sizeof(int));        // 3.2 MB
    float* eww    = (float*)alloc((size_t)E * sizeof(float));      // 3.2 MB
    int*   rowptr = (int*)  alloc((size_t)(N + 1) * sizeof(int));
    int*   deg    = (int*)  alloc((size_t)N * sizeof(int));
    int*   cursor = (int*)  alloc((size_t)N * sizeof(int));
    int*   bsum   = (int*)  alloc(1024 * sizeof(int));

    const int NB = (N + 1023) / 1024;
    const int gemmGrid = (N + 127) / 128;

    // ---- CSR build (shared by both layers) ----
    hipMemsetAsync(deg, 0, (size_t)N * sizeof(int), stream);
    hist_kernel <<<(E + 255) / 256, 256, 0, stream>>>(src, deg, E);
    scan1_kernel<<<NB, 1024, 0, stream>>>(deg, rowptr, bsum, N);
    scan2_kernel<<<1, 1024, 0, stream>>>(bsum, NB);
    scan3_kernel<<<(N + 255) / 256, 256, 0, stream>>>(deg, bsum, rowptr, cursor, N);
    fill_kernel <<<(E + 255) / 256, 256, 0, stream>>>(src, dst, ew, cursor, edst, eww, E);

    // ---- Layer 1 ----
    aggregate_kernel<<<(N + 3) / 4, 256, 0, stream>>>(x, rowptr, edst, eww, neigh, N);
    sage_gemm<<<gemmGrid, 256, 0, stream>>>(x, neigh, W1, b1, h, N);

    // ---- Layer 2 ----
    aggregate_kernel<<<(N + 3) / 4, 256, 0, stream>>>(h, rowptr, edst, eww, neigh, N);
    sage_gemm<<<gemmGrid, 256, 0, stream>>>(h, neigh, W2, b2, out, N);

    // ---- Normalize ----
    normalize_kernel<<<(N + 3) / 4, 256, 0, stream>>>(out, N);
}

// Round 3
// 395.573 us; speedup vs baseline: 7.5954x; 1.1738x over previous
//
#include <hip/hip_runtime.h>
#include <hip/hip_bf16.h>

#define D 128

typedef __attribute__((ext_vector_type(8))) short bf16x8;
typedef __attribute__((ext_vector_type(4))) float f32x4;
typedef unsigned short u16;
typedef unsigned int u32;

// fp32 -> bf16 round-to-nearest-even, bit-level
__device__ inline u16 f2bf(float f) {
    union { float f; u32 u; } v; v.f = f;
    u32 r = v.u + 0x7FFFu + ((v.u >> 16) & 1u);
    return (u16)(r >> 16);
}

// ---------------------------------------------------------------------------
// fp32 -> bf16 cast, 4 elements/thread
// ---------------------------------------------------------------------------
__global__ void cast_kernel(const float* __restrict__ in, u16* __restrict__ out, int n4) {
    int i = blockIdx.x * blockDim.x + threadIdx.x;
    if (i < n4) {
        float4 v = *(const float4*)(in + (size_t)i * 4);
        u32 lo = (u32)f2bf(v.x) | ((u32)f2bf(v.y) << 16);
        u32 hi = (u32)f2bf(v.z) | ((u32)f2bf(v.w) << 16);
        *(uint2*)(out + (size_t)i * 4) = make_uint2(lo, hi);
    }
}

// ---------------------------------------------------------------------------
// CSR build: histogram of src, scan -> rowptr, bucket-fill dst/w.
// ---------------------------------------------------------------------------
__global__ void hist_kernel(const int* __restrict__ src, int* __restrict__ deg, int E) {
    int i = blockIdx.x * blockDim.x + threadIdx.x;
    if (i < E) atomicAdd(&deg[src[i]], 1);
}

__global__ void scan1_kernel(const int* __restrict__ deg, int* __restrict__ rowptr,
                             int* __restrict__ bsum, int n) {
    __shared__ int s[1024];
    int t = threadIdx.x;
    int i = blockIdx.x * 1024 + t;
    int v = (i < n) ? deg[i] : 0;
    s[t] = v;
    __syncthreads();
    for (int off = 1; off < 1024; off <<= 1) {
        int x = (t >= off) ? s[t - off] : 0;
        __syncthreads();
        s[t] += x;
        __syncthreads();
    }
    if (i < n) rowptr[i + 1] = s[t];
    if (t == 1023) bsum[blockIdx.x] = s[t];
}

__global__ void scan2_kernel(int* __restrict__ bsum, int nb) {
    __shared__ int s[1024];
    int t = threadIdx.x;
    int v = (t < nb) ? bsum[t] : 0;
    s[t] = v;
    __syncthreads();
    for (int off = 1; off < 1024; off <<= 1) {
        int x = (t >= off) ? s[t - off] : 0;
        __syncthreads();
        s[t] += x;
        __syncthreads();
    }
    if (t < nb) bsum[t] = (t == 0) ? 0 : s[t - 1];
}

__global__ void scan3_kernel(const int* __restrict__ deg, const int* __restrict__ bsum,
                             int* __restrict__ rowptr, int* __restrict__ cursor, int n) {
    int i = blockIdx.x * blockDim.x + threadIdx.x;
    if (i < n) {
        int v = rowptr[i + 1] + bsum[i >> 10];
        rowptr[i + 1] = v;
        cursor[i] = v - deg[i];
    }
    if (i == 0) rowptr[0] = 0;
}

__global__ void fill_kernel(const int* __restrict__ src, const int* __restrict__ dst,
                            const float* __restrict__ w, int* __restrict__ cursor,
                            int* __restrict__ edst, float* __restrict__ eww, int E) {
    int i = blockIdx.x * blockDim.x + threadIdx.x;
    if (i < E) {
        int p = atomicAdd(&cursor[src[i]], 1);
        edst[p] = dst[i];
        eww[p] = w[i];
    }
}

// ---------------------------------------------------------------------------
// Gather aggregation (bf16 features): one wave per node; lane holds 2 feats.
// neigh[node] = bf16( sum_e w_e*feat[dst_e] / max(sum_e w_e, eps) )
// ---------------------------------------------------------------------------
__global__ void aggregate_kernel(const u16* __restrict__ feat,
                                 const int* __restrict__ rowptr,
                                 const int* __restrict__ edst,
                                 const float* __restrict__ eww,
                                 u16* __restrict__ neigh, int n) {
    int node = blockIdx.x * 4 + (threadIdx.x >> 6);
    if (node >= n) return;
    int lane = threadIdx.x & 63;
    int beg = rowptr[node];
    int end = rowptr[node + 1];
    float ax = 0.f, ay = 0.f, ws = 0.f;
    int j = beg;
    for (; j + 3 < end; j += 4) {   // 4 gathers in flight
        int d0 = edst[j], d1 = edst[j + 1], d2 = edst[j + 2], d3 = edst[j + 3];
        float w0 = eww[j], w1 = eww[j + 1], w2 = eww[j + 2], w3 = eww[j + 3];
        u32 u0 = *(const u32*)(feat + (size_t)d0 * D + lane * 2);
        u32 u1 = *(const u32*)(feat + (size_t)d1 * D + lane * 2);
        u32 u2 = *(const u32*)(feat + (size_t)d2 * D + lane * 2);
        u32 u3 = *(const u32*)(feat + (size_t)d3 * D + lane * 2);
        ax += __uint_as_float(u0 << 16) * w0 + __uint_as_float(u1 << 16) * w1
            + __uint_as_float(u2 << 16) * w2 + __uint_as_float(u3 << 16) * w3;
        ay += __uint_as_float(u0 & 0xFFFF0000u) * w0 + __uint_as_float(u1 & 0xFFFF0000u) * w1
            + __uint_as_float(u2 & 0xFFFF0000u) * w2 + __uint_as_float(u3 & 0xFFFF0000u) * w3;
        ws += w0 + w1 + w2 + w3;
    }
    for (; j < end; ++j) {
        int d0 = edst[j];
        float w0 = eww[j];
        u32 u0 = *(const u32*)(feat + (size_t)d0 * D + lane * 2);
        ax += __uint_as_float(u0 << 16) * w0;
        ay += __uint_as_float(u0 & 0xFFFF0000u) * w0;
        ws += w0;
    }
    float inv = 1.0f / fmaxf(ws, 1e-12f);
    u32 o = (u32)f2bf(ax * inv) | ((u32)f2bf(ay * inv) << 16);
    *(u32*)(neigh + (size_t)node * D + lane * 2) = o;
}

// ---------------------------------------------------------------------------
// Fused SAGE GEMM, bf16 A-path. out[r][o] = relu( sum_k A[r][k]*W[o][k] + b[o] )
// A[r][k] = axb[r][k] (k<128) else aneigh[r][k-128]; both bf16 [n][128].
// NORM=false: store bf16 h.  NORM=true: row-L2-normalize in-epilogue, store f32.
// ---------------------------------------------------------------------------
template <bool NORM>
__global__ void __launch_bounds__(256)
sage_gemm(const u16* __restrict__ axb,
          const u16* __restrict__ aneigh,
          const float* __restrict__ W,     // [128][256] fp32
          const float* __restrict__ bias,  // [128]
          u16* __restrict__ outB,          // NORM=false
          float* __restrict__ outF,        // NORM=true
          int n) {
    __shared__ short As[128][72];   // 144B rows: 16B-aligned, 2-way bank alias free
    __shared__ short Bs[128][72];

    const int row0 = blockIdx.x * 128;
    const int tid  = threadIdx.x;
    const int wave = tid >> 6;
    const int lane = tid & 63;
    const int quad = lane >> 4;
    const int l16  = lane & 15;

    f32x4 acc[2][8];
#pragma unroll
    for (int rt = 0; rt < 2; ++rt)
#pragma unroll
        for (int c = 0; c < 8; ++c)
            acc[rt][c] = (f32x4){0.f, 0.f, 0.f, 0.f};

#pragma unroll
    for (int kc = 0; kc < 4; ++kc) {
        const u16* asrc = (kc >= 2) ? aneigh : axb;
        const int cbase = (kc & 1) * 64;

        // A stage: bf16 direct copy, 16B per thread-iter
#pragma unroll
        for (int i = 0; i < 4; ++i) {
            int e = i * 256 + tid;          // 0..1023
            int r = e >> 3;                  // 0..127
            int c8 = (e & 7) * 8;            // 0..56
            int row = row0 + r;
            if (row >= n) row = n - 1;       // clamp; garbage rows never stored
            *(uint4*)(&As[r][c8]) = *(const uint4*)(asrc + (size_t)row * D + cbase + c8);
        }
        // B stage: fp32 W -> bf16
#pragma unroll
        for (int i = 0; i < 8; ++i) {
            int e = i * 256 + tid;
            int r = e >> 4;
            int c4 = (e & 15) * 4;
            float4 wv = *(const float4*)(W + (size_t)r * 256 + kc * 64 + c4);
            u32 wlo = (u32)f2bf(wv.x) | ((u32)f2bf(wv.y) << 16);
            u32 whi = (u32)f2bf(wv.z) | ((u32)f2bf(wv.w) << 16);
            *(uint2*)(&Bs[r][c4]) = make_uint2(wlo, whi);
        }
        __syncthreads();

#pragma unroll
        for (int ks = 0; ks < 2; ++ks) {
            const int koff = ks * 32 + quad * 8;
            bf16x8 a0 = *(const bf16x8*)&As[wave * 32 + l16][koff];
            bf16x8 a1 = *(const bf16x8*)&As[wave * 32 + 16 + l16][koff];
#pragma unroll
            for (int c = 0; c < 8; ++c) {
                bf16x8 b = *(const bf16x8*)&Bs[c * 16 + l16][koff];
                acc[0][c] = __builtin_amdgcn_mfma_f32_16x16x32_bf16(a0, b, acc[0][c], 0, 0, 0);
                acc[1][c] = __builtin_amdgcn_mfma_f32_16x16x32_bf16(a1, b, acc[1][c], 0, 0, 0);
            }
        }
        __syncthreads();
    }

    // Epilogue. C/D layout: col=lane&15, row=quad*4+reg.
    float bvals[8];
#pragma unroll
    for (int c = 0; c < 8; ++c) bvals[c] = bias[c * 16 + l16];

#pragma unroll
    for (int rt = 0; rt < 2; ++rt) {
#pragma unroll
        for (int reg = 0; reg < 4; ++reg) {
            int row = row0 + wave * 32 + rt * 16 + quad * 4 + reg;
            if (row >= n) continue;
            float v[8];
#pragma unroll
            for (int c = 0; c < 8; ++c)
                v[c] = fmaxf(acc[rt][c][reg] + bvals[c], 0.0f);
            if (NORM) {
                // row lives in the 16 lanes of this quad (l16=0..15), 8 vals each
                float ss = 0.f;
#pragma unroll
                for (int c = 0; c < 8; ++c) ss += v[c] * v[c];
                ss += __shfl_xor(ss, 1);
                ss += __shfl_xor(ss, 2);
                ss += __shfl_xor(ss, 4);
                ss += __shfl_xor(ss, 8);
                float inv = 1.0f / fmaxf(sqrtf(ss), 1e-12f);
                float* orow = outF + (size_t)row * D;
#pragma unroll
                for (int c = 0; c < 8; ++c)
                    orow[c * 16 + l16] = v[c] * inv;
            } else {
                u16* orow = outB + (size_t)row * D;
#pragma unroll
                for (int c = 0; c < 8; ++c)
                    orow[c * 16 + l16] = f2bf(v[c]);
            }
        }
    }
}

extern "C" void kernel_launch(void* const* d_in, const int* in_sizes, int n_in,
                              void* d_out, int out_size, void* d_ws, size_t ws_size,
                              hipStream_t stream) {
    const float* x  = (const float*)d_in[0];
    const int*   ei = (const int*)d_in[1];   // [2, E]: row 0 = src, row 1 = dst
    const float* ew = (const float*)d_in[2];
    const float* W1 = (const float*)d_in[3];
    const float* b1 = (const float*)d_in[4];
    const float* W2 = (const float*)d_in[5];
    const float* b2 = (const float*)d_in[6];
    float* out = (float*)d_out;

    const int E = in_sizes[2];
    const int N = in_sizes[0] / D;

    const int* src = ei;
    const int* dst = ei + E;

    // workspace layout
    char* p = (char*)d_ws;
    auto alloc = [&](size_t bytes) { char* r = p; p += (bytes + 255) & ~(size_t)255; return r; };
    u16*   xb     = (u16*)  alloc((size_t)N * D * sizeof(u16));   // 25.6 MB
    u16*   hB     = (u16*)  alloc((size_t)N * D * sizeof(u16));   // 25.6 MB
    u16*   neighB = (u16*)  alloc((size_t)N * D * sizeof(u16));   // 25.6 MB
    int*   edst   = (int*)  alloc((size_t)E * sizeof(int));       // 3.2 MB
    float* eww    = (float*)alloc((size_t)E * sizeof(float));     // 3.2 MB
    int*   rowptr = (int*)  alloc((size_t)(N + 1) * sizeof(int));
    int*   deg    = (int*)  alloc((size_t)N * sizeof(int));
    int*   cursor = (int*)  alloc((size_t)N * sizeof(int));
    int*   bsum   = (int*)  alloc(1024 * sizeof(int));

    const int NB = (N + 1023) / 1024;
    const int gemmGrid = (N + 127) / 128;
    const int n4 = N * D / 4;

    // ---- CSR build + x cast ----
    hipMemsetAsync(deg, 0, (size_t)N * sizeof(int), stream);
    hist_kernel <<<(E + 255) / 256, 256, 0, stream>>>(src, deg, E);
    scan1_kernel<<<NB, 1024, 0, stream>>>(deg, rowptr, bsum, N);
    scan2_kernel<<<1, 1024, 0, stream>>>(bsum, NB);
    scan3_kernel<<<(N + 255) / 256, 256, 0, stream>>>(deg, bsum, rowptr, cursor, N);
    fill_kernel <<<(E + 255) / 256, 256, 0, stream>>>(src, dst, ew, cursor, edst, eww, E);
    cast_kernel <<<(n4 + 255) / 256, 256, 0, stream>>>(x, xb, n4);

    // ---- Layer 1 ----
    aggregate_kernel<<<(N + 3) / 4, 256, 0, stream>>>(xb, rowptr, edst, eww, neighB, N);
    sage_gemm<false><<<gemmGrid, 256, 0, stream>>>(xb, neighB, W1, b1, hB, nullptr, N);

    // ---- Layer 2 (normalize fused into epilogue) ----
    aggregate_kernel<<<(N + 3) / 4, 256, 0, stream>>>(hB, rowptr, edst, eww, neighB, N);
    sage_gemm<true><<<gemmGrid, 256, 0, stream>>>(hB, neighB, W2, b2, nullptr, out, N);
}